// Round 1
// baseline (782.304 us; speedup 1.0000x reference)
//
#include <hip/hip_runtime.h>

// Problem constants (fixed by the reference)
#define B_  4
#define SQ_ 4096
#define SK_ 462
#define H_  10
#define DH_ 64
#define D_  (H_ * DH_)   // 640

typedef _Float16 half8 __attribute__((ext_vector_type(8)));
typedef float floatx4 __attribute__((ext_vector_type(4)));

// ---------------------------------------------------------------------------
// mask_bool storage-format detection: 0 = int32 per element, 1 = byte per
// element, 2 = float32 per element. Values are only 0/1 (True guaranteed at
// [...,0]). int32 dwords are {0,1}; byte-packed dwords show nonzero high
// bytes w.h.p. within 4 KiB; float shows 0x3F800000.
// ---------------------------------------------------------------------------
__global__ void detect_mask_fmt(const unsigned int* __restrict__ mb_dw,
                                int* __restrict__ flag) {
  __shared__ int s_float, s_byte;
  if (threadIdx.x == 0) { s_float = 0; s_byte = 0; }
  __syncthreads();
  int fl = 0, by = 0;
  for (int i = threadIdx.x; i < 1024; i += 256) {
    unsigned int x = mb_dw[i];
    if (x > 1u) {
      if (x == 0x3F800000u) fl = 1; else by = 1;
    }
  }
  if (fl) atomicOr(&s_float, 1);
  if (by) atomicOr(&s_byte, 1);
  __syncthreads();
  if (threadIdx.x == 0) flag[0] = s_float ? 2 : (s_byte ? 1 : 0);
}

// ---------------------------------------------------------------------------
// Flash-style masked cross attention.
// grid = (SQ/64, H, B), block = 256 (4 waves); wave owns 16 query rows.
// mfma_f32_16x16x32_f16 layouts (HW-verified per guide):
//   A[m=lane&15][k=(lane>>4)*8+j],  B[k=(lane>>4)*8+j][n=lane&15],
//   C/D: col=lane&15, row=(lane>>4)*4+reg.
// ---------------------------------------------------------------------------
__global__ __launch_bounds__(256)
void attn_fwd(const float* __restrict__ q, const float* __restrict__ k,
              const float* __restrict__ v, const void* __restrict__ mb,
              const float* __restrict__ msc, float* __restrict__ out,
              const int* __restrict__ flag) {
  // LDS: ~29.6 KB total -> LDS allows 5 blocks/CU
  __shared__ __align__(16) float    qs[64][65];      // q tile fp32, odd dword stride
  __shared__ __align__(16) _Float16 ks[32][66];      // K chunk [key][dim], stride 66 halves = 33 dw (odd)
  __shared__ __align__(16) _Float16 vts[64][34];     // V chunk transposed [dim][key], 17 dw (odd)
  __shared__ __align__(16) _Float16 ps[4][16][34];   // per-wave P relayout buffer

  const int tid  = threadIdx.x;
  const int wave = tid >> 6;
  const int lane = tid & 63;
  const int l16  = lane & 15;
  const int g4   = lane >> 4;

  const int b  = blockIdx.z;
  const int h  = blockIdx.y;
  const int q0 = blockIdx.x * 64;
  const int fmt = flag[0];

  // ---- stage Q tile (64 rows x 64 dims), coalesced float4 ----
  {
    const float* qbase = q + (size_t)(b * SQ_ + q0) * D_ + h * DH_;
    #pragma unroll
    for (int i = 0; i < 4; ++i) {
      int idx4 = tid + i * 256;        // 0..1023
      int row  = idx4 >> 4;
      int d4   = (idx4 & 15) * 4;
      float4 val = *reinterpret_cast<const float4*>(qbase + (size_t)row * D_ + d4);
      qs[row][d4 + 0] = val.x; qs[row][d4 + 1] = val.y;
      qs[row][d4 + 2] = val.z; qs[row][d4 + 3] = val.w;
    }
  }
  __syncthreads();

  // ---- Q A-fragments, kept in regs for all K iterations ----
  half8 aq[2];
  {
    int row = wave * 16 + l16;
    #pragma unroll
    for (int kk = 0; kk < 2; ++kk) {
      int dbase = kk * 32 + g4 * 8;
      #pragma unroll
      for (int j = 0; j < 8; ++j) aq[kk][j] = (_Float16)qs[row][dbase + j];
    }
  }

  floatx4 o_acc[4];
  floatx4 l_acc;
  #pragma unroll
  for (int nt = 0; nt < 4; ++nt)
    #pragma unroll
    for (int r = 0; r < 4; ++r) o_acc[nt][r] = 0.0f;
  #pragma unroll
  for (int r = 0; r < 4; ++r) l_acc[r] = 0.0f;

  float m2[4] = {-1e30f, -1e30f, -1e30f, -1e30f};  // running max, base-2 domain

  unsigned int rowoff[4];
  #pragma unroll
  for (int r = 0; r < 4; ++r) {
    int qrow = q0 + wave * 16 + g4 * 4 + r;
    rowoff[r] = (unsigned int)((b * H_ + h) * SQ_ + qrow) * SK_;
  }

  half8 ones_f;
  #pragma unroll
  for (int j = 0; j < 8; ++j) ones_f[j] = (_Float16)1.0f;

  const float c2 = 0.18033688011112042f;  // (1/sqrt(64)) * log2(e)

  const float* kbase = k + (size_t)(b * SK_) * D_ + h * DH_;
  const float* vbase = v + (size_t)(b * SK_) * D_ + h * DH_;

  const int KT = (SK_ + 31) / 32;  // 15
  for (int kt = 0; kt < KT; ++kt) {
    __syncthreads();  // protect ks/vts from previous iteration's readers

    // ---- cooperative stage: K chunk + V chunk (transposed), fp32 -> f16 ----
    #pragma unroll
    for (int i = 0; i < 2; ++i) {
      int idx4 = tid + i * 256;        // 0..511
      int key  = idx4 >> 4;            // 0..31
      int d4   = (idx4 & 15) * 4;
      int gk   = kt * 32 + key;
      int gkc  = gk < SK_ ? gk : SK_ - 1;   // clamp: finite garbage, masked later
      bool okk = gk < SK_;
      float4 kvv = *reinterpret_cast<const float4*>(kbase + (size_t)gkc * D_ + d4);
      float4 vvv = *reinterpret_cast<const float4*>(vbase + (size_t)gkc * D_ + d4);
      ks[key][d4 + 0] = (_Float16)kvv.x; ks[key][d4 + 1] = (_Float16)kvv.y;
      ks[key][d4 + 2] = (_Float16)kvv.z; ks[key][d4 + 3] = (_Float16)kvv.w;
      // V padding MUST be zero (p==0 would still propagate NaN from junk LDS)
      vts[d4 + 0][key] = okk ? (_Float16)vvv.x : (_Float16)0.0f;
      vts[d4 + 1][key] = okk ? (_Float16)vvv.y : (_Float16)0.0f;
      vts[d4 + 2][key] = okk ? (_Float16)vvv.z : (_Float16)0.0f;
      vts[d4 + 3][key] = okk ? (_Float16)vvv.w : (_Float16)0.0f;
    }

    // ---- mask loads (global, issued before the barrier to absorb latency) --
    float mscv[2][4];
    int   mval[2][4];
    #pragma unroll
    for (int ct = 0; ct < 2; ++ct) {
      #pragma unroll
      for (int r = 0; r < 4; ++r) {
        int col = kt * 32 + ct * 16 + l16;
        int cc  = col < SK_ ? col : SK_ - 1;
        unsigned int idx = rowoff[r] + (unsigned int)cc;
        mscv[ct][r] = msc[idx];
        int mv;
        if (fmt == 1)      mv = ((const unsigned char*)mb)[idx] != 0;
        else if (fmt == 0) mv = ((const int*)mb)[idx] != 0;
        else               mv = ((const float*)mb)[idx] != 0.0f;
        mval[ct][r] = (col < SK_) ? mv : 0;
      }
    }
    __syncthreads();

    // ---- S = Q K^T (16 rows x 32 keys per wave) ----
    floatx4 s[2];
    #pragma unroll
    for (int ct = 0; ct < 2; ++ct)
      #pragma unroll
      for (int r = 0; r < 4; ++r) s[ct][r] = 0.0f;
    #pragma unroll
    for (int ct = 0; ct < 2; ++ct) {
      int key = ct * 16 + l16;
      #pragma unroll
      for (int kk = 0; kk < 2; ++kk) {
        half8 kb;
        int dbase = kk * 32 + g4 * 8;
        #pragma unroll
        for (int j = 0; j < 8; ++j) kb[j] = ks[key][dbase + j];
        s[ct] = __builtin_amdgcn_mfma_f32_16x16x32_f16(aq[kk], kb, s[ct], 0, 0, 0);
      }
    }

    // ---- online softmax (base-2) ----
    float pv[2][4];
    #pragma unroll
    for (int r = 0; r < 4; ++r) {
      float s0 = s[0][r] * (c2 * mscv[0][r]);
      float s1 = s[1][r] * (c2 * mscv[1][r]);
      s0 = mval[0][r] ? s0 : -1e30f;
      s1 = mval[1][r] ? s1 : -1e30f;
      float mx = fmaxf(s0, s1);
      mx = fmaxf(mx, __shfl_xor(mx, 1));
      mx = fmaxf(mx, __shfl_xor(mx, 2));
      mx = fmaxf(mx, __shfl_xor(mx, 4));
      mx = fmaxf(mx, __shfl_xor(mx, 8));
      float mnew  = fmaxf(m2[r], mx);
      float alpha = exp2f(m2[r] - mnew);
      m2[r] = mnew;
      pv[0][r] = exp2f(s0 - mnew);   // masked: exp2(-1e30 - finite) == +0
      pv[1][r] = exp2f(s1 - mnew);
      l_acc[r] *= alpha;
      #pragma unroll
      for (int nt = 0; nt < 4; ++nt) o_acc[nt][r] *= alpha;
    }

    // ---- P: C-layout -> A-layout via per-wave LDS round-trip ----
    #pragma unroll
    for (int ct = 0; ct < 2; ++ct)
      #pragma unroll
      for (int r = 0; r < 4; ++r)
        ps[wave][g4 * 4 + r][ct * 16 + l16] = (_Float16)pv[ct][r];
    asm volatile("s_waitcnt lgkmcnt(0)" ::: "memory");  // wave-local write->read
    half8 pa;
    #pragma unroll
    for (int j = 0; j < 8; ++j) pa[j] = ps[wave][l16][g4 * 8 + j];

    // ---- O += P V ; l += rowsum(P) via ones-column MFMA ----
    #pragma unroll
    for (int nt = 0; nt < 4; ++nt) {
      half8 vb;
      int dim = nt * 16 + l16;
      #pragma unroll
      for (int j = 0; j < 8; ++j) vb[j] = vts[dim][g4 * 8 + j];
      o_acc[nt] = __builtin_amdgcn_mfma_f32_16x16x32_f16(pa, vb, o_acc[nt], 0, 0, 0);
    }
    l_acc = __builtin_amdgcn_mfma_f32_16x16x32_f16(pa, ones_f, l_acc, 0, 0, 0);
  }

  // ---- epilogue: normalize and store (16-lane, 64B coalesced segments) ----
  #pragma unroll
  for (int r = 0; r < 4; ++r) {
    float inv = 1.0f / l_acc[r];
    int qrow = q0 + wave * 16 + g4 * 4 + r;
    float* ob = out + (size_t)(b * SQ_ + qrow) * D_ + h * DH_;
    #pragma unroll
    for (int nt = 0; nt < 4; ++nt)
      ob[nt * 16 + l16] = o_acc[nt][r] * inv;
  }
}

extern "C" void kernel_launch(void* const* d_in, const int* in_sizes, int n_in,
                              void* d_out, int out_size, void* d_ws, size_t ws_size,
                              hipStream_t stream) {
  const float* q   = (const float*)d_in[0];
  const float* k   = (const float*)d_in[1];
  const float* v   = (const float*)d_in[2];
  const void*  mb  = d_in[3];          // mask_bool: storage format auto-detected
  const float* msc = (const float*)d_in[4];
  // d_in[5] = heads (==10), constant for this problem
  float* out = (float*)d_out;
  int*   flg = (int*)d_ws;

  detect_mask_fmt<<<1, 256, 0, stream>>>((const unsigned int*)mb, flg);
  dim3 grid(SQ_ / 64, H_, B_);
  attn_fwd<<<grid, 256, 0, stream>>>(q, k, v, mb, msc, out, flg);
}